// Round 6
// baseline (5728.046 us; speedup 1.0000x reference)
//
#include <hip/hip_runtime.h>
#include <hip/hip_bf16.h>
#include <math.h>

// GGNN: L=5 layers of { m = h@W_l ; agg = scatter_add(ew * m[src] -> dst) ;
//                       h = GRUCell(agg, h) } then out = relu(h)@fc_w^T + fc_b
// H=256, N=50000, E=800000.
//
// R10-R14: m97-style gates GEMM (128x128 tile, BK=64 2-slab, dead-MFMA
//   skips) proven at 162us/dispatch.
// R15: weight folding (agg@Wih^T = S@(Wih@W_l^T)^T) deleted m_gemm; layer
//   loop = { spmm(h) -> gates }. But the epilogue's packed-hlin write doubled
//   gates' WRITE_SIZE (54->110MB) -> gates 162->203us.
// R16 (this round): drop hlin; spmm gathers DIRECTLY from the tiled HH/HL
//   planes (4-consecutive-k slice = contiguous 8B-aligned ushort4). Same
//   bytes gathered, zero extra writes in gates. useHL=0 falls back to
//   hi-only gather (matches pre-R15 semantics).

#define HDIM 256

using bf16x8 = __attribute__((ext_vector_type(8))) short;
using f32x4  = __attribute__((ext_vector_type(4))) float;

__device__ __forceinline__ bf16x8 ldfrag(const ushort* p) {
    union { uint4 u; bf16x8 f; } x;
    x.u = *(const uint4*)p;
    return x.f;
}
#define MFMA(a, b, c) __builtin_amdgcn_mfma_f32_16x16x32_bf16((a), (b), (c), 0, 0, 0)
#define GLD16(g, l)                                                            \
    __builtin_amdgcn_global_load_lds(                                          \
        (const __attribute__((address_space(1))) void*)(g),                    \
        (__attribute__((address_space(3))) void*)(l), 16, 0, 0)

__device__ __forceinline__ float ldf(const void* p, size_t i, int isbf) {
    if (isbf) return __bfloat162float(((const __hip_bfloat16*)p)[i]);
    return ((const float*)p)[i];
}
__device__ __forceinline__ ushort f2bs(float v) {
    __hip_bfloat16 b = __float2bfloat16(v);
    return *(ushort*)&b;
}
__device__ __forceinline__ float bs2f(ushort u) {
    __hip_bfloat16 b = *(__hip_bfloat16*)&u;
    return __bfloat162float(b);
}
// tiled plane addr, K-extent 256 (h planes): 16x32 fragment tiles of 512 halves
__device__ __forceinline__ size_t taddrH(int n, int k) {
    return (size_t)(n >> 4) * 4096 + (size_t)((k >> 5) << 9)
         + (size_t)(((k >> 3) & 3) << 7) + (size_t)((n & 15) << 3) + (k & 7);
}
// tiled plane addr, K-extent 512 (S hi|lo combined)
__device__ __forceinline__ size_t taddrA(int n, int k) {
    return (size_t)(n >> 4) * 8192 + (size_t)((k >> 5) << 9)
         + (size_t)(((k >> 3) & 3) << 7) + (size_t)((n & 15) << 3) + (k & 7);
}

// flags[0] = 1 if float tensors are bf16, 0 if f32
// flags[1] = 1 if edge_index is int64, 0 if int32
__global__ void detect_k(const void* x, const void* ei, int* flags) {
    if (blockIdx.x == 0 && threadIdx.x == 0) {
        const __hip_bfloat16* xb = (const __hip_bfloat16*)x;
        int isbf = 1;
        for (int i = 0; i < 1024; ++i) {
            float v = fabsf(__bfloat162float(xb[i]));
            if (!(v < 1e6f)) { isbf = 0; break; }
        }
        flags[0] = isbf;
        const int* e32 = (const int*)ei;
        int orv = e32[1] | e32[3] | e32[5] | e32[7] | e32[9] | e32[11];
        flags[1] = (orv == 0) ? 1 : 0;
    }
}

// x -> h planes (tiled); pad rows zeroed
__global__ void conv_h0_k(const void* x, ushort* HH, ushort* HL,
                          const int* flags, int useHL, int Nn, size_t npad256) {
    size_t i = (size_t)blockIdx.x * blockDim.x + threadIdx.x;
    if (i >= npad256) return;
    const int n = (int)(i >> 8), k = (int)(i & 255);
    float v = 0.f;
    if (n < Nn) v = ldf(x, i, flags[0]);
    const ushort hi = f2bs(v);
    const size_t a = taddrH(n, k);
    HH[a] = hi;
    if (useHL) HL[a] = f2bs(v - bs2f(hi));
}

// WihP[l][r][k] = sum_j Wih[r][j] * W[l][k][j]  (f32, 16x16-tiled, LDS-staged)
__global__ __launch_bounds__(256)
void prep1_k(const void* wih, const void* w, float* wihp, const int* flags) {
    __shared__ float As[16][260], Bs[16][260];
    const int bx = blockIdx.x;            // l*768 + rt16*16 + kt16
    const int l = bx / 768, rem = bx % 768;
    const int rt = (rem >> 4) << 4, kt = (rem & 15) << 4;
    const int tid = threadIdx.x, isbf = flags[0];
    for (int idx = tid; idx < 4096; idx += 256) {
        const int row = idx >> 8, col = idx & 255;
        As[row][col] = ldf(wih, (size_t)(rt + row) * 256 + col, isbf);
        Bs[row][col] = ldf(w, (size_t)l * 65536 + (size_t)(kt + row) * 256 + col, isbf);
    }
    __syncthreads();
    const int ri = tid >> 4, ki = tid & 15;
    float acc = 0.f;
    for (int j = 0; j < 256; ++j) acc = fmaf(As[ri][j], Bs[ki][j], acc);
    wihp[((size_t)l * 768 + rt + ri) * 256 + kt + ki] = acc;
}

// Build tiled gate-B matrices + biases.
// BgA[l] [1024 out][512 k] (k segs = S hi / S lo), out col j: g=(j>>4)&3,
//   b=16*(j>>6)+(j&15): g in {r,z,ni}: WihP[l][g*256+b][kk]; nh: 0.
// BgB (shared) [1024 out][512 k] (k segs = h hi / h lo): g in {r,z}:
//   Whh[g*256+b][kk]; nh: Whh[512+b][kk]; ni: 0.
__global__ void prep2_k(const float* __restrict__ wihp, const void* whh,
                        const void* bih, const void* bhh,
                        ushort* BgAH, ushort* BgAL, ushort* BgBH, ushort* BgBL,
                        float* bsum, float* bni, float* bnh,
                        const int* flags, int L) {
    const int i = blockIdx.x * blockDim.x + threadIdx.x;
    const int isbf = flags[0];
    if (i < (L << 19)) {
        const int l = i >> 19, r2 = i & 524287;
        const int j = r2 >> 9, k = r2 & 511;
        const int g = (j >> 4) & 3, b = ((j >> 6) << 4) + (j & 15);
        const int kk = k & 255;
        const float v = (g == 3) ? 0.f
                      : wihp[((size_t)l * 768 + g * 256 + b) * 256 + kk];
        const ushort hi = f2bs(v);
        const int ct = j >> 4, c = k >> 5;
        const size_t a = (size_t)l * 524288 + (size_t)(ct * 16 + c) * 512
                       + (size_t)(((k >> 3) & 3) << 7) + ((j & 15) << 3) + (k & 7);
        BgAH[a] = hi; BgAL[a] = f2bs(v - bs2f(hi));
    }
    if (i < 524288) {
        const int j = i >> 9, k = i & 511;
        const int g = (j >> 4) & 3, b = ((j >> 6) << 4) + (j & 15);
        const int kk = k & 255;
        float v;
        if (g == 0)      v = ldf(whh, (size_t)b * 256 + kk, isbf);
        else if (g == 1) v = ldf(whh, (size_t)(256 + b) * 256 + kk, isbf);
        else if (g == 2) v = 0.f;
        else             v = ldf(whh, (size_t)(512 + b) * 256 + kk, isbf);
        const ushort hi = f2bs(v);
        const int ct = j >> 4, c = k >> 5;
        const size_t a = (size_t)(ct * 16 + c) * 512
                       + (size_t)(((k >> 3) & 3) << 7) + ((j & 15) << 3) + (k & 7);
        BgBH[a] = hi; BgBL[a] = f2bs(v - bs2f(hi));
    }
    if (i < 512) bsum[i] = ldf(bih, i, isbf) + ldf(bhh, i, isbf);
    if (i < 256) {
        bni[i] = ldf(bih, 512 + i, isbf);
        bnh[i] = ldf(bhh, 512 + i, isbf);
    }
}

// ---------------- CSR build (by dst), once per call ----------------

__global__ void zero_int_k(int* p, int n) {
    int i = blockIdx.x * blockDim.x + threadIdx.x;
    if (i < n) p[i] = 0;
}

__global__ void count_k(const void* ei, int* cnt, const int* flags, int E) {
    int e = blockIdx.x * blockDim.x + threadIdx.x;
    if (e >= E) return;
    const int* e32 = (const int*)ei;
    int d = flags[1] ? e32[2 * ((size_t)E + e)] : e32[(size_t)E + e];
    atomicAdd(&cnt[d], 1);
}

__global__ __launch_bounds__(256)
void scan1_k(const int* cnt, int* ptr, int* bsumN, int N) {
    __shared__ int s[256];
    const int t = threadIdx.x;
    const int gid = blockIdx.x * 256 + t;
    int v = (gid < N) ? cnt[gid] : 0;
    const int own = v;
    s[t] = v;
    __syncthreads();
#pragma unroll
    for (int off = 1; off < 256; off <<= 1) {
        int add = (t >= off) ? s[t - off] : 0;
        __syncthreads();
        s[t] += add;
        __syncthreads();
    }
    if (gid < N) ptr[gid] = s[t] - own;
    if (t == 255) bsumN[blockIdx.x] = s[255];
}

__global__ __launch_bounds__(256)
void scan2_k(int* bsumN, int NB) {
    __shared__ int s[256];
    __shared__ int carry;
    const int t = threadIdx.x;
    if (t == 0) carry = 0;
    __syncthreads();
    for (int base = 0; base < NB; base += 256) {
        const int i = base + t;
        int v = (i < NB) ? bsumN[i] : 0;
        const int own = v;
        s[t] = v;
        __syncthreads();
#pragma unroll
        for (int off = 1; off < 256; off <<= 1) {
            int add = (t >= off) ? s[t - off] : 0;
            __syncthreads();
            s[t] += add;
            __syncthreads();
        }
        if (i < NB) bsumN[i] = carry + s[t] - own;
        __syncthreads();
        if (t == 0) carry += s[255];
        __syncthreads();
    }
}

__global__ void scan3_k(int* ptr, int* cursor, const int* bsumN, int N, int E) {
    const int gid = blockIdx.x * 256 + threadIdx.x;
    if (gid < N) {
        const int p = ptr[gid] + bsumN[blockIdx.x];
        ptr[gid] = p;
        cursor[gid] = p;
    }
    if (gid == 0) ptr[N] = E;
}

__global__ void fill_k(const void* ei, const void* ew, int* cursor,
                       int* srcs, float* wse, const int* flags, int E) {
    int e = blockIdx.x * blockDim.x + threadIdx.x;
    if (e >= E) return;
    const int* e32 = (const int*)ei;
    int s, d;
    if (flags[1]) { s = e32[2 * (size_t)e]; d = e32[2 * ((size_t)E + e)]; }
    else          { s = e32[e];             d = e32[(size_t)E + e]; }
    const int p = atomicAdd(&cursor[d], 1);
    srcs[p] = s;
    wse[p] = ldf(ew, e, flags[0]);
}

// ---------------- SpMM gather: S[d] = sum_j w_j * h[src_j] ------------------
// Gathers straight from the tiled HH/HL planes: a row's 4-consecutive-k slice
// is a contiguous 8B-aligned ushort4. Accumulates f32, writes S combined
// plane (hi at k, lo at 256+k), tiled layout.
__global__ __launch_bounds__(256)
void spmm_k(const ushort* __restrict__ HH, const ushort* __restrict__ HL,
            const int* __restrict__ ptr, const int* __restrict__ srcs,
            const float* __restrict__ wse, ushort* __restrict__ AGG,
            int useHL, int N) {
    const int node = blockIdx.x * 4 + (threadIdx.x >> 6);
    if (node >= N) return;
    const int lane = threadIdx.x & 63;
    const int lane4 = lane << 2;
    // lane-constant part of taddrH(n, lane4..lane4+3)
    const size_t kpart = (size_t)((lane4 >> 5) << 9)
                       + (size_t)(((lane4 >> 3) & 3) << 7) + (size_t)(lane4 & 7);
    const int p0 = ptr[node], p1 = ptr[node + 1];
    float4 acc = make_float4(0.f, 0.f, 0.f, 0.f);
    if (useHL) {
        int j = p0;
        for (; j + 1 < p1; j += 2) {
            const int s0 = srcs[j], s1 = srcs[j + 1];
            const float w0 = wse[j], w1 = wse[j + 1];
            const size_t a0 = (size_t)(s0 >> 4) * 4096 + (size_t)((s0 & 15) << 3) + kpart;
            const size_t a1 = (size_t)(s1 >> 4) * 4096 + (size_t)((s1 & 15) << 3) + kpart;
            const ushort4 h0 = *(const ushort4*)&HH[a0];
            const ushort4 l0 = *(const ushort4*)&HL[a0];
            const ushort4 h1 = *(const ushort4*)&HH[a1];
            const ushort4 l1 = *(const ushort4*)&HL[a1];
            acc.x = fmaf(w0, bs2f(h0.x) + bs2f(l0.x), acc.x);
            acc.y = fmaf(w0, bs2f(h0.y) + bs2f(l0.y), acc.y);
            acc.z = fmaf(w0, bs2f(h0.z) + bs2f(l0.z), acc.z);
            acc.w = fmaf(w0, bs2f(h0.w) + bs2f(l0.w), acc.w);
            acc.x = fmaf(w1, bs2f(h1.x) + bs2f(l1.x), acc.x);
            acc.y = fmaf(w1, bs2f(h1.y) + bs2f(l1.y), acc.y);
            acc.z = fmaf(w1, bs2f(h1.z) + bs2f(l1.z), acc.z);
            acc.w = fmaf(w1, bs2f(h1.w) + bs2f(l1.w), acc.w);
        }
        if (j < p1) {
            const int s0 = srcs[j];
            const float w0 = wse[j];
            const size_t a0 = (size_t)(s0 >> 4) * 4096 + (size_t)((s0 & 15) << 3) + kpart;
            const ushort4 h0 = *(const ushort4*)&HH[a0];
            const ushort4 l0 = *(const ushort4*)&HL[a0];
            acc.x = fmaf(w0, bs2f(h0.x) + bs2f(l0.x), acc.x);
            acc.y = fmaf(w0, bs2f(h0.y) + bs2f(l0.y), acc.y);
            acc.z = fmaf(w0, bs2f(h0.z) + bs2f(l0.z), acc.z);
            acc.w = fmaf(w0, bs2f(h0.w) + bs2f(l0.w), acc.w);
        }
    } else {
        for (int j = p0; j < p1; ++j) {
            const int s0 = srcs[j];
            const float w0 = wse[j];
            const size_t a0 = (size_t)(s0 >> 4) * 4096 + (size_t)((s0 & 15) << 3) + kpart;
            const ushort4 h0 = *(const ushort4*)&HH[a0];
            acc.x = fmaf(w0, bs2f(h0.x), acc.x);
            acc.y = fmaf(w0, bs2f(h0.y), acc.y);
            acc.z = fmaf(w0, bs2f(h0.z), acc.z);
            acc.w = fmaf(w0, bs2f(h0.w), acc.w);
        }
    }
    ushort4 hi, lo;
    hi.x = f2bs(acc.x); lo.x = f2bs(acc.x - bs2f(hi.x));
    hi.y = f2bs(acc.y); lo.y = f2bs(acc.y - bs2f(hi.y));
    hi.z = f2bs(acc.z); lo.z = f2bs(acc.z - bs2f(hi.z));
    hi.w = f2bs(acc.w); lo.w = f2bs(acc.w - bs2f(hi.w));
    *(ushort4*)&AGG[taddrA(node, lane4)] = hi;
    *(ushort4*)&AGG[taddrA(node, 256 + lane4)] = lo;
}

// ---------------- gates GEMM + fused GRU (R12 BK=64 2-slab structure) -------
// A = [S hi (c0..7) | S lo (c8..15) | hH (c16..23) | hL (c24..31)].
// B = BgA[l] for c<16 (K=512, 16 chunks), BgB shared for c>=16.
// Wave's 4 col-tiles = (r,z,ni,nh) for 16 hidden units -> local GRU epilogue.
// JSKIP=3 (nh zero on S segs), JSKIP=2 (ni zero on h segs); lo-B only on
// A-hi regions (skip lo*lo). B next-ct-row stride = 16*512 = 8192.
__global__ __launch_bounds__(256)
void gates_k(const ushort* __restrict__ AGG,
             const ushort* __restrict__ HH, const ushort* __restrict__ HL,
             const ushort* __restrict__ BgAH, const ushort* __restrict__ BgAL,
             const ushort* __restrict__ BgBH, const ushort* __restrict__ BgBL,
             const float* __restrict__ bsum, const float* __restrict__ bni,
             const float* __restrict__ bnh,
             ushort* __restrict__ HnH, ushort* __restrict__ HnL,
             const int* __restrict__ flags, int useHL, int nRB) {
    __shared__ ushort lds[24576];  // 2 slabs x (A 4096 | Bh 4096 | Bl 4096)
    const int x = blockIdx.x & 7, rem = blockIdx.x >> 3;
    const int cgB = rem & 7, rbHi = rem >> 3;
    const int rb = rbHi * 8 + x;
    if (rb >= nRB) return;
    const int tid = threadIdx.x, lane = tid & 63;
    const int wv = __builtin_amdgcn_readfirstlane(tid >> 6);
    const int wr = wv & 1, wc = wv >> 1;
    const int lm = lane & 15, lq = lane >> 4;
    const int fullsplit = !flags[0];
    const int rt = rb * 8, t0 = 2 * wv;
    f32x4 acc[4][4];
#pragma unroll
    for (int i = 0; i < 4; ++i)
#pragma unroll
        for (int j = 0; j < 4; ++j) acc[i][j] = (f32x4){0.f, 0.f, 0.f, 0.f};

// One BK=64 step = local chunks c0l, c0l+1 of B matrix {BH,BL} (NC=16).
#define GT_STEP(BH, BL, c0l, A0, ASTRIDE, JSKIP, DOLO)                         \
    do {                                                                       \
        __syncthreads();                                                       \
        GLD16((A0) + (size_t)lane * 8, &lds[t0 * 512]);                        \
        GLD16((A0) + (ASTRIDE) + (size_t)lane * 8, &lds[t0 * 512 + 512]);      \
        GLD16((A0) + 512 + (size_t)lane * 8, &lds[12288 + t0 * 512]);          \
        GLD16((A0) + (ASTRIDE) + 512 + (size_t)lane * 8, &lds[12288 + t0 * 512 + 512]); \
        const size_t bb = ((size_t)(8 * cgB + t0) * 16 + (size_t)(c0l)) * 512; \
        if ((t0 & 3) != (JSKIP)) {                                             \
            GLD16((BH) + bb + (size_t)lane * 8, &lds[4096 + t0 * 512]);        \
            GLD16((BH) + bb + 512 + (size_t)lane * 8, &lds[12288 + 4096 + t0 * 512]); \
        }                                                                      \
        if (((t0 + 1) & 3) != (JSKIP)) {                                       \
            GLD16((BH) + bb + 8192 + (size_t)lane * 8, &lds[4096 + t0 * 512 + 512]); \
            GLD16((BH) + bb + 8704 + (size_t)lane * 8, &lds[12288 + 4096 + t0 * 512 + 512]); \
        }                                                                      \
        if (DOLO) {                                                            \
            if ((t0 & 3) != (JSKIP)) {                                         \
                GLD16((BL) + bb + (size_t)lane * 8, &lds[8192 + t0 * 512]);    \
                GLD16((BL) + bb + 512 + (size_t)lane * 8, &lds[12288 + 8192 + t0 * 512]); \
            }                                                                  \
            if (((t0 + 1) & 3) != (JSKIP)) {                                   \
                GLD16((BL) + bb + 8192 + (size_t)lane * 8, &lds[8192 + t0 * 512 + 512]); \
                GLD16((BL) + bb + 8704 + (size_t)lane * 8, &lds[12288 + 8192 + t0 * 512 + 512]); \
            }                                                                  \
        }                                                                      \
        __syncthreads();                                                       \
        _Pragma("unroll")                                                      \
        for (int sb = 0; sb < 2; ++sb) {                                       \
            const int lb = sb * 12288;                                         \
            bf16x8 af[4];                                                      \
            _Pragma("unroll")                                                  \
            for (int i = 0; i < 4; ++i)                                        \
                af[i] = ldfrag(&lds[lb + (4 * wr + i) * 512 + lq * 128 + lm * 8]); \
            _Pragma("unroll")                                                  \
            for (int j = 0; j < 4; ++j) {                                      \
                if (j == (JSKIP)) continue;                                    \
                const bf16x8 bj = ldfrag(&lds[lb + 4096 + (4 * wc + j) * 512 + lq * 128 + lm * 8]); \
                _Pragma("unroll")                                              \
                for (int i = 0; i < 4; ++i) acc[i][j] = MFMA(af[i], bj, acc[i][j]); \
            }                                                                  \
            if (DOLO) {                                                        \
                _Pragma("unroll")                                              \
                for (int j = 0; j < 4; ++j) {                                  \
                    if (j == (JSKIP)) continue;                                \
                    const bf16x8 bl = ldfrag(&lds[lb + 8192 + (4 * wc + j) * 512 + lq * 128 + lm * 8]); \
                    _Pragma("unroll")                                          \
                    for (int i = 0; i < 4; ++i) acc[i][j] = MFMA(af[i], bl, acc[i][j]); \
                }                                                              \
            }                                                                  \
        }                                                                      \
    } while (0)

    // region 0: chunks 0..7   A = S hi (lo-B if fullsplit)
    for (int s = 0; s < 4; ++s) {
        const ushort* a0 = AGG + (size_t)(rt + t0) * 8192 + (size_t)(2 * s) * 512;
        GT_STEP(BgAH, BgAL, 2 * s, a0, 8192, 3, fullsplit);
    }
    // region 1: chunks 8..15  A = S lo (no lo-B: lo*lo dropped)
    for (int s = 4; s < 8; ++s) {
        const ushort* a0 = AGG + (size_t)(rt + t0) * 8192 + (size_t)(2 * s) * 512;
        GT_STEP(BgAH, BgAL, 2 * s, a0, 8192, 3, 0);
    }
    // region 2: chunks 16..23 A = hH (lo-B if fullsplit)
    for (int s = 8; s < 12; ++s) {
        const ushort* a0 = HH + (size_t)(rt + t0) * 4096 + (size_t)(2 * s - 16) * 512;
        GT_STEP(BgBH, BgBL, 2 * s - 16, a0, 4096, 2, fullsplit);
    }
    // region 3: chunks 24..31 A = hL (no lo-B)
    if (useHL) {
        for (int s = 12; s < 16; ++s) {
            const ushort* a0 = HL + (size_t)(rt + t0) * 4096 + (size_t)(2 * s - 24) * 512;
            GT_STEP(BgBH, BgBL, 2 * s - 16, a0, 4096, 2, 0);
        }
    }
#undef GT_STEP

    // GRU epilogue: col-tile 0..3 = r,z,ni,nh for hidden unit b
    const int b = (2 * cgB + wc) * 16 + lm;
    const float rbias = bsum[b], zbias = bsum[256 + b];
    const float ibias = bni[b], hbias = bnh[b];
#pragma unroll
    for (int i = 0; i < 4; ++i) {
        const int row0 = rb * 128 + wr * 64 + i * 16 + lq * 4;
#pragma unroll
        for (int v = 0; v < 4; ++v) {
            const int row = row0 + v;
            const size_t ho = taddrH(row, b);  // buffers padded; pads benign
            float hold = bs2f(HH[ho]);
            if (useHL) hold += bs2f(HL[ho]);
            const float r = 1.f / (1.f + expf(-(acc[i][0][v] + rbias)));
            const float z = 1.f / (1.f + expf(-(acc[i][1][v] + zbias)));
            const float nn = tanhf(acc[i][2][v] + ibias + r * (acc[i][3][v] + hbias));
            const float hv = (1.f - z) * nn + z * hold;
            const ushort hi = f2bs(hv);
            HnH[ho] = hi;
            if (useHL) HnL[ho] = f2bs(hv - bs2f(hi));
        }
    }
}

// out[n] = sum_t relu(h[n,t]) * fc_w[t] + fc_b ; one 256-thread block per node
__global__ void final_k(const ushort* __restrict__ HH, const ushort* __restrict__ HL,
                        const void* fcw, const void* fcb,
                        void* out, const int* flags, int useHL, int N) {
    const int n = blockIdx.x;
    const int t = threadIdx.x;
    const int isbf = flags[0];
    const size_t off = taddrH(n, t);
    float h = bs2f(HH[off]);
    if (useHL) h += bs2f(HL[off]);
    float v = fmaxf(h, 0.f) * ldf(fcw, t, isbf);
#pragma unroll
    for (int offx = 32; offx >= 1; offx >>= 1) v += __shfl_down(v, offx);
    __shared__ float red[4];
    if ((t & 63) == 0) red[t >> 6] = v;
    __syncthreads();
    if (t == 0) {
        const float s = red[0] + red[1] + red[2] + red[3] + ldf(fcb, 0, isbf);
        if (isbf) ((__hip_bfloat16*)out)[n] = __float2bfloat16(s);
        else      ((float*)out)[n] = s;
    }
}

extern "C" void kernel_launch(void* const* d_in, const int* in_sizes, int n_in,
                              void* d_out, int out_size, void* d_ws, size_t ws_size,
                              hipStream_t stream) {
    const int H = HDIM;
    const int N = in_sizes[0] / H;       // 50000
    const int E = in_sizes[2];           // 800000
    const int L = in_sizes[3] / (H * H); // 5
    const int NB = (N + 255) / 256;
    const int nRB = (N + 127) / 128;     // 391
    const size_t NPAD = (size_t)nRB * 128;
    const size_t hHalf = NPAD * 256;     // halves per h plane
    const size_t aggHalf = NPAD * 512;

    char* p = (char*)d_ws;
    int*    flags = (int*)p;              p += 64;
    ushort* AGG  = (ushort*)p;            p += aggHalf * 2;
    ushort* HxH  = (ushort*)p;            p += hHalf * 2;
    ushort* HyH  = (ushort*)p;            p += hHalf * 2;
    float*  wihp = (float*)p;             p += (size_t)L * 768 * 256 * 4;
    ushort* BgAH = (ushort*)p;            p += (size_t)L * 524288 * 2;
    ushort* BgAL = (ushort*)p;            p += (size_t)L * 524288 * 2;
    ushort* BgBH = (ushort*)p;            p += (size_t)524288 * 2;
    ushort* BgBL = (ushort*)p;            p += (size_t)524288 * 2;
    float*  bsum = (float*)p;             p += 512 * 4;
    float*  bni  = (float*)p;             p += 256 * 4;
    float*  bnh  = (float*)p;             p += 256 * 4;
    int*    ptr  = (int*)p;               p += (size_t)(N + 1) * 4;
    int*    cursor = (int*)p;             p += (size_t)N * 4;
    int*    bsumN  = (int*)p;             p += (size_t)NB * 4;
    int*    srcs   = (int*)p;             p += (size_t)E * 4;
    float*  wse    = (float*)p;           p += (size_t)E * 4;
    const size_t need_reduced = (size_t)(p - (char*)d_ws);
    ushort* HxL = (ushort*)p;             // optional hi/lo h planes
    ushort* HyL = (ushort*)(p + hHalf * 2);
    const size_t need_full = need_reduced + 2 * hHalf * 2;
    const int useHL = (ws_size >= need_full) ? 1 : 0;
    if (!useHL) { HxL = HxH; HyL = HyH; }  // never dereferenced when useHL=0

    detect_k<<<dim3(1), dim3(64), 0, stream>>>(d_in[0], d_in[1], flags);
    conv_h0_k<<<dim3((unsigned)NPAD), dim3(256), 0, stream>>>(
        d_in[0], HxH, HxL, flags, useHL, N, NPAD * 256);
    prep1_k<<<dim3((unsigned)(L * 768)), dim3(256), 0, stream>>>(
        d_in[4], d_in[3], wihp, flags);
    prep2_k<<<dim3((unsigned)(L * 2048)), dim3(256), 0, stream>>>(
        wihp, d_in[5], d_in[6], d_in[7],
        BgAH, BgAL, BgBH, BgBL, bsum, bni, bnh, flags, L);

    zero_int_k<<<dim3(NB), dim3(256), 0, stream>>>(cursor, N);
    count_k<<<dim3((E + 255) / 256), dim3(256), 0, stream>>>(d_in[1], cursor, flags, E);
    scan1_k<<<dim3(NB), dim3(256), 0, stream>>>(cursor, ptr, bsumN, N);
    scan2_k<<<dim3(1), dim3(256), 0, stream>>>(bsumN, NB);
    scan3_k<<<dim3(NB), dim3(256), 0, stream>>>(ptr, cursor, bsumN, N, E);
    fill_k<<<dim3((E + 255) / 256), dim3(256), 0, stream>>>(
        d_in[1], d_in[2], cursor, srcs, wse, flags, E);

    const dim3 blk(256);
    const unsigned gGrid = 64u * (unsigned)((nRB + 7) / 8);
    ushort *HcH = HxH, *HcL = HxL, *HnH = HyH, *HnL = HyL;
    for (int l = 0; l < L; ++l) {
        spmm_k<<<dim3((N + 3) / 4), blk, 0, stream>>>(
            HcH, HcL, ptr, srcs, wse, AGG, useHL, N);
        gates_k<<<dim3(gGrid), blk, 0, stream>>>(
            AGG, HcH, HcL,
            BgAH + (size_t)l * 524288, BgAL + (size_t)l * 524288,
            BgBH, BgBL, bsum, bni, bnh, HnH, HnL, flags, useHL, nRB);
        ushort* t;
        t = HcH; HcH = HnH; HnH = t;
        t = HcL; HcL = HnL; HnL = t;
    }
    final_k<<<dim3(N), blk, 0, stream>>>(
        HcH, HcL, d_in[8], d_in[9], d_out, flags, useHL, N);
}

// Round 7
// 1904.090 us; speedup vs baseline: 3.0083x; 3.0083x over previous
//
#include <hip/hip_runtime.h>
#include <hip/hip_bf16.h>
#include <math.h>

// GGNN: L=5 layers of { m = h@W_l ; agg = scatter_add(ew * m[src] -> dst) ;
//                       h = GRUCell(agg, h) } then out = relu(h)@fc_w^T + fc_b
// H=256, N=50000, E=800000.
//
// R10-R14: m97-style gates GEMM (128x128 tile, BK=64 2-slab, dead-MFMA
//   skips) proven at 162us/dispatch.
// R15: weight folding deleted m_gemm (agg@Wih^T = S@(Wih@W_l^T)^T).
// R16: spmm gathered from TILED h planes -> 4x overfetch (16B per 64B line,
//   FETCH 3.18GB/dispatch), spmm 948us. Tiled layout is hostile to gather.
// R17 (this round): h planes stored LINEAR [n][256]. spmm gather is fully
//   coalesced (512B/edge/plane contiguous). gates stages h A-fragments from
//   linear layout via PER-LANE global_load_lds sources (m173: glds src is
//   per-lane; LDS dest stays linear): lane l reads 16B at
//   base + (l&15)*256 + (l>>4)*8 + chunk*32 -> 16 x 64B fully-used segments.
//   AGG stays tiled (written by spmm, staged uniformly). No repack, no dup.

#define HDIM 256

using bf16x8 = __attribute__((ext_vector_type(8))) short;
using f32x4  = __attribute__((ext_vector_type(4))) float;

__device__ __forceinline__ bf16x8 ldfrag(const ushort* p) {
    union { uint4 u; bf16x8 f; } x;
    x.u = *(const uint4*)p;
    return x.f;
}
#define MFMA(a, b, c) __builtin_amdgcn_mfma_f32_16x16x32_bf16((a), (b), (c), 0, 0, 0)
#define GLD16(g, l)                                                            \
    __builtin_amdgcn_global_load_lds(                                          \
        (const __attribute__((address_space(1))) void*)(g),                    \
        (__attribute__((address_space(3))) void*)(l), 16, 0, 0)

__device__ __forceinline__ float ldf(const void* p, size_t i, int isbf) {
    if (isbf) return __bfloat162float(((const __hip_bfloat16*)p)[i]);
    return ((const float*)p)[i];
}
__device__ __forceinline__ ushort f2bs(float v) {
    __hip_bfloat16 b = __float2bfloat16(v);
    return *(ushort*)&b;
}
__device__ __forceinline__ float bs2f(ushort u) {
    __hip_bfloat16 b = *(__hip_bfloat16*)&u;
    return __bfloat162float(b);
}
// tiled plane addr, K-extent 512 (S hi|lo combined) — AGG only
__device__ __forceinline__ size_t taddrA(int n, int k) {
    return (size_t)(n >> 4) * 8192 + (size_t)((k >> 5) << 9)
         + (size_t)(((k >> 3) & 3) << 7) + (size_t)((n & 15) << 3) + (k & 7);
}

// flags[0] = 1 if float tensors are bf16, 0 if f32
// flags[1] = 1 if edge_index is int64, 0 if int32
__global__ void detect_k(const void* x, const void* ei, int* flags) {
    if (blockIdx.x == 0 && threadIdx.x == 0) {
        const __hip_bfloat16* xb = (const __hip_bfloat16*)x;
        int isbf = 1;
        for (int i = 0; i < 1024; ++i) {
            float v = fabsf(__bfloat162float(xb[i]));
            if (!(v < 1e6f)) { isbf = 0; break; }
        }
        flags[0] = isbf;
        const int* e32 = (const int*)ei;
        int orv = e32[1] | e32[3] | e32[5] | e32[7] | e32[9] | e32[11];
        flags[1] = (orv == 0) ? 1 : 0;
    }
}

// x -> linear h planes; pad rows zeroed
__global__ void conv_h0_k(const void* x, ushort* HH, ushort* HL,
                          const int* flags, int useHL, int Nn, size_t npad256) {
    size_t i = (size_t)blockIdx.x * blockDim.x + threadIdx.x;
    if (i >= npad256) return;
    float v = 0.f;
    if ((int)(i >> 8) < Nn) v = ldf(x, i, flags[0]);
    const ushort hi = f2bs(v);
    HH[i] = hi;
    if (useHL) HL[i] = f2bs(v - bs2f(hi));
}

// WihP[l][r][k] = sum_j Wih[r][j] * W[l][k][j]  (f32, 16x16-tiled, LDS-staged)
__global__ __launch_bounds__(256)
void prep1_k(const void* wih, const void* w, float* wihp, const int* flags) {
    __shared__ float As[16][260], Bs[16][260];
    const int bx = blockIdx.x;            // l*768 + rt16*16 + kt16
    const int l = bx / 768, rem = bx % 768;
    const int rt = (rem >> 4) << 4, kt = (rem & 15) << 4;
    const int tid = threadIdx.x, isbf = flags[0];
    for (int idx = tid; idx < 4096; idx += 256) {
        const int row = idx >> 8, col = idx & 255;
        As[row][col] = ldf(wih, (size_t)(rt + row) * 256 + col, isbf);
        Bs[row][col] = ldf(w, (size_t)l * 65536 + (size_t)(kt + row) * 256 + col, isbf);
    }
    __syncthreads();
    const int ri = tid >> 4, ki = tid & 15;
    float acc = 0.f;
    for (int j = 0; j < 256; ++j) acc = fmaf(As[ri][j], Bs[ki][j], acc);
    wihp[((size_t)l * 768 + rt + ri) * 256 + kt + ki] = acc;
}

// Build tiled gate-B matrices + biases.
// BgA[l] [1024 out][512 k] (k segs = S hi / S lo), out col j: g=(j>>4)&3,
//   b=16*(j>>6)+(j&15): g in {r,z,ni}: WihP[l][g*256+b][kk]; nh: 0.
// BgB (shared) [1024 out][512 k] (k segs = h hi / h lo): g in {r,z}:
//   Whh[g*256+b][kk]; nh: Whh[512+b][kk]; ni: 0.
__global__ void prep2_k(const float* __restrict__ wihp, const void* whh,
                        const void* bih, const void* bhh,
                        ushort* BgAH, ushort* BgAL, ushort* BgBH, ushort* BgBL,
                        float* bsum, float* bni, float* bnh,
                        const int* flags, int L) {
    const int i = blockIdx.x * blockDim.x + threadIdx.x;
    const int isbf = flags[0];
    if (i < (L << 19)) {
        const int l = i >> 19, r2 = i & 524287;
        const int j = r2 >> 9, k = r2 & 511;
        const int g = (j >> 4) & 3, b = ((j >> 6) << 4) + (j & 15);
        const int kk = k & 255;
        const float v = (g == 3) ? 0.f
                      : wihp[((size_t)l * 768 + g * 256 + b) * 256 + kk];
        const ushort hi = f2bs(v);
        const int ct = j >> 4, c = k >> 5;
        const size_t a = (size_t)l * 524288 + (size_t)(ct * 16 + c) * 512
                       + (size_t)(((k >> 3) & 3) << 7) + ((j & 15) << 3) + (k & 7);
        BgAH[a] = hi; BgAL[a] = f2bs(v - bs2f(hi));
    }
    if (i < 524288) {
        const int j = i >> 9, k = i & 511;
        const int g = (j >> 4) & 3, b = ((j >> 6) << 4) + (j & 15);
        const int kk = k & 255;
        float v;
        if (g == 0)      v = ldf(whh, (size_t)b * 256 + kk, isbf);
        else if (g == 1) v = ldf(whh, (size_t)(256 + b) * 256 + kk, isbf);
        else if (g == 2) v = 0.f;
        else             v = ldf(whh, (size_t)(512 + b) * 256 + kk, isbf);
        const ushort hi = f2bs(v);
        const int ct = j >> 4, c = k >> 5;
        const size_t a = (size_t)(ct * 16 + c) * 512
                       + (size_t)(((k >> 3) & 3) << 7) + ((j & 15) << 3) + (k & 7);
        BgBH[a] = hi; BgBL[a] = f2bs(v - bs2f(hi));
    }
    if (i < 512) bsum[i] = ldf(bih, i, isbf) + ldf(bhh, i, isbf);
    if (i < 256) {
        bni[i] = ldf(bih, 512 + i, isbf);
        bnh[i] = ldf(bhh, 512 + i, isbf);
    }
}

// ---------------- CSR build (by dst), once per call ----------------

__global__ void zero_int_k(int* p, int n) {
    int i = blockIdx.x * blockDim.x + threadIdx.x;
    if (i < n) p[i] = 0;
}

__global__ void count_k(const void* ei, int* cnt, const int* flags, int E) {
    int e = blockIdx.x * blockDim.x + threadIdx.x;
    if (e >= E) return;
    const int* e32 = (const int*)ei;
    int d = flags[1] ? e32[2 * ((size_t)E + e)] : e32[(size_t)E + e];
    atomicAdd(&cnt[d], 1);
}

__global__ __launch_bounds__(256)
void scan1_k(const int* cnt, int* ptr, int* bsumN, int N) {
    __shared__ int s[256];
    const int t = threadIdx.x;
    const int gid = blockIdx.x * 256 + t;
    int v = (gid < N) ? cnt[gid] : 0;
    const int own = v;
    s[t] = v;
    __syncthreads();
#pragma unroll
    for (int off = 1; off < 256; off <<= 1) {
        int add = (t >= off) ? s[t - off] : 0;
        __syncthreads();
        s[t] += add;
        __syncthreads();
    }
    if (gid < N) ptr[gid] = s[t] - own;
    if (t == 255) bsumN[blockIdx.x] = s[255];
}

__global__ __launch_bounds__(256)
void scan2_k(int* bsumN, int NB) {
    __shared__ int s[256];
    __shared__ int carry;
    const int t = threadIdx.x;
    if (t == 0) carry = 0;
    __syncthreads();
    for (int base = 0; base < NB; base += 256) {
        const int i = base + t;
        int v = (i < NB) ? bsumN[i] : 0;
        const int own = v;
        s[t] = v;
        __syncthreads();
#pragma unroll
        for (int off = 1; off < 256; off <<= 1) {
            int add = (t >= off) ? s[t - off] : 0;
            __syncthreads();
            s[t] += add;
            __syncthreads();
        }
        if (i < NB) bsumN[i] = carry + s[t] - own;
        __syncthreads();
        if (t == 0) carry += s[255];
        __syncthreads();
    }
}

__global__ void scan3_k(int* ptr, int* cursor, const int* bsumN, int N, int E) {
    const int gid = blockIdx.x * 256 + threadIdx.x;
    if (gid < N) {
        const int p = ptr[gid] + bsumN[blockIdx.x];
        ptr[gid] = p;
        cursor[gid] = p;
    }
    if (gid == 0) ptr[N] = E;
}

__global__ void fill_k(const void* ei, const void* ew, int* cursor,
                       int* srcs, float* wse, const int* flags, int E) {
    int e = blockIdx.x * blockDim.x + threadIdx.x;
    if (e >= E) return;
    const int* e32 = (const int*)ei;
    int s, d;
    if (flags[1]) { s = e32[2 * (size_t)e]; d = e32[2 * ((size_t)E + e)]; }
    else          { s = e32[e];             d = e32[(size_t)E + e]; }
    const int p = atomicAdd(&cursor[d], 1);
    srcs[p] = s;
    wse[p] = ldf(ew, e, flags[0]);
}

// ---------------- SpMM gather: S[d] = sum_j w_j * h[src_j] ------------------
// Gathers from LINEAR h planes (512B contiguous per edge per plane),
// accumulates f32, writes S combined plane (hi at k, lo at 256+k), tiled.
__global__ __launch_bounds__(256)
void spmm_k(const ushort* __restrict__ HH, const ushort* __restrict__ HL,
            const int* __restrict__ ptr, const int* __restrict__ srcs,
            const float* __restrict__ wse, ushort* __restrict__ AGG,
            int useHL, int N) {
    const int node = blockIdx.x * 4 + (threadIdx.x >> 6);
    if (node >= N) return;
    const int lane = threadIdx.x & 63;
    const int lane4 = lane << 2;
    const int p0 = ptr[node], p1 = ptr[node + 1];
    float4 acc = make_float4(0.f, 0.f, 0.f, 0.f);
    if (useHL) {
        int j = p0;
        for (; j + 1 < p1; j += 2) {
            const int s0 = srcs[j], s1 = srcs[j + 1];
            const float w0 = wse[j], w1 = wse[j + 1];
            const ushort4 h0 = *(const ushort4*)&HH[(size_t)s0 * 256 + lane4];
            const ushort4 l0 = *(const ushort4*)&HL[(size_t)s0 * 256 + lane4];
            const ushort4 h1 = *(const ushort4*)&HH[(size_t)s1 * 256 + lane4];
            const ushort4 l1 = *(const ushort4*)&HL[(size_t)s1 * 256 + lane4];
            acc.x = fmaf(w0, bs2f(h0.x) + bs2f(l0.x), acc.x);
            acc.y = fmaf(w0, bs2f(h0.y) + bs2f(l0.y), acc.y);
            acc.z = fmaf(w0, bs2f(h0.z) + bs2f(l0.z), acc.z);
            acc.w = fmaf(w0, bs2f(h0.w) + bs2f(l0.w), acc.w);
            acc.x = fmaf(w1, bs2f(h1.x) + bs2f(l1.x), acc.x);
            acc.y = fmaf(w1, bs2f(h1.y) + bs2f(l1.y), acc.y);
            acc.z = fmaf(w1, bs2f(h1.z) + bs2f(l1.z), acc.z);
            acc.w = fmaf(w1, bs2f(h1.w) + bs2f(l1.w), acc.w);
        }
        if (j < p1) {
            const int s0 = srcs[j];
            const float w0 = wse[j];
            const ushort4 h0 = *(const ushort4*)&HH[(size_t)s0 * 256 + lane4];
            const ushort4 l0 = *(const ushort4*)&HL[(size_t)s0 * 256 + lane4];
            acc.x = fmaf(w0, bs2f(h0.x) + bs2f(l0.x), acc.x);
            acc.y = fmaf(w0, bs2f(h0.y) + bs2f(l0.y), acc.y);
            acc.z = fmaf(w0, bs2f(h0.z) + bs2f(l0.z), acc.z);
            acc.w = fmaf(w0, bs2f(h0.w) + bs2f(l0.w), acc.w);
        }
    } else {
        for (int j = p0; j < p1; ++j) {
            const int s0 = srcs[j];
            const float w0 = wse[j];
            const ushort4 h0 = *(const ushort4*)&HH[(size_t)s0 * 256 + lane4];
            acc.x = fmaf(w0, bs2f(h0.x), acc.x);
            acc.y = fmaf(w0, bs2f(h0.y), acc.y);
            acc.z = fmaf(w0, bs2f(h0.z), acc.z);
            acc.w = fmaf(w0, bs2f(h0.w), acc.w);
        }
    }
    ushort4 hi, lo;
    hi.x = f2bs(acc.x); lo.x = f2bs(acc.x - bs2f(hi.x));
    hi.y = f2bs(acc.y); lo.y = f2bs(acc.y - bs2f(hi.y));
    hi.z = f2bs(acc.z); lo.z = f2bs(acc.z - bs2f(hi.z));
    hi.w = f2bs(acc.w); lo.w = f2bs(acc.w - bs2f(hi.w));
    *(ushort4*)&AGG[taddrA(node, lane4)] = hi;
    *(ushort4*)&AGG[taddrA(node, 256 + lane4)] = lo;
}

// ---------------- gates GEMM + fused GRU (R12 BK=64 2-slab structure) -------
// A = [S hi (c0..7) | S lo (c8..15) | hH (c16..23) | hL (c24..31)].
// B = BgA[l] for c<16, BgB shared for c>=16 (each 16 chunks, ct-row stride
// 8192). AGG staged with uniform srcs (tiled); h regions staged from LINEAR
// planes with per-lane srcs: lane l -> (row=l&15, k=(l>>4)*8) of the chunk.
// JSKIP=3 (nh zero on S segs), JSKIP=2 (ni zero on h segs); lo-B only on
// A-hi regions (skip lo*lo). All skip conditions wave-uniform.
__global__ __launch_bounds__(256)
void gates_k(const ushort* __restrict__ AGG,
             const ushort* __restrict__ HH, const ushort* __restrict__ HL,
             const ushort* __restrict__ BgAH, const ushort* __restrict__ BgAL,
             const ushort* __restrict__ BgBH, const ushort* __restrict__ BgBL,
             const float* __restrict__ bsum, const float* __restrict__ bni,
             const float* __restrict__ bnh,
             ushort* __restrict__ HnH, ushort* __restrict__ HnL,
             const int* __restrict__ flags, int useHL, int nRB) {
    __shared__ ushort lds[24576];  // 2 slabs x (A 4096 | Bh 4096 | Bl 4096)
    const int x = blockIdx.x & 7, rem = blockIdx.x >> 3;
    const int cgB = rem & 7, rbHi = rem >> 3;
    const int rb = rbHi * 8 + x;
    if (rb >= nRB) return;
    const int tid = threadIdx.x, lane = tid & 63;
    const int wv = __builtin_amdgcn_readfirstlane(tid >> 6);
    const int wr = wv & 1, wc = wv >> 1;
    const int lm = lane & 15, lq = lane >> 4;
    const int fullsplit = !flags[0];
    const int rt = rb * 8, t0 = 2 * wv;
    // per-lane source offset for linear h staging (halves)
    const size_t hoff = (size_t)lm * 256 + (size_t)lq * 8;
    f32x4 acc[4][4];
#pragma unroll
    for (int i = 0; i < 4; ++i)
#pragma unroll
        for (int j = 0; j < 4; ++j) acc[i][j] = (f32x4){0.f, 0.f, 0.f, 0.f};

// One BK=64 step = local chunks c0l, c0l+1 of B matrix {BH,BL} (NC=16).
// AS00/AS01/AS10/AS11: per-lane A srcs (slab0 rows0/rows1, slab1 rows0/rows1).
#define GT_STEP(BH, BL, c0l, AS00, AS01, AS10, AS11, JSKIP, DOLO)              \
    do {                                                                       \
        __syncthreads();                                                       \
        GLD16((AS00), &lds[t0 * 512]);                                         \
        GLD16((AS01), &lds[t0 * 512 + 512]);                                   \
        GLD16((AS10), &lds[12288 + t0 * 512]);                                 \
        GLD16((AS11), &lds[12288 + t0 * 512 + 512]);                           \
        const size_t bb = ((size_t)(8 * cgB + t0) * 16 + (size_t)(c0l)) * 512; \
        if ((t0 & 3) != (JSKIP)) {                                             \
            GLD16((BH) + bb + (size_t)lane * 8, &lds[4096 + t0 * 512]);        \
            GLD16((BH) + bb + 512 + (size_t)lane * 8, &lds[12288 + 4096 + t0 * 512]); \
        }                                                                      \
        if (((t0 + 1) & 3) != (JSKIP)) {                                       \
            GLD16((BH) + bb + 8192 + (size_t)lane * 8, &lds[4096 + t0 * 512 + 512]); \
            GLD16((BH) + bb + 8704 + (size_t)lane * 8, &lds[12288 + 4096 + t0 * 512 + 512]); \
        }                                                                      \
        if (DOLO) {                                                            \
            if ((t0 & 3) != (JSKIP)) {                                         \
                GLD16((BL) + bb + (size_t)lane * 8, &lds[8192 + t0 * 512]);    \
                GLD16((BL) + bb + 512 + (size_t)lane * 8, &lds[12288 + 8192 + t0 * 512]); \
            }                                                                  \
            if (((t0 + 1) & 3) != (JSKIP)) {                                   \
                GLD16((BL) + bb + 8192 + (size_t)lane * 8, &lds[8192 + t0 * 512 + 512]); \
                GLD16((BL) + bb + 8704 + (size_t)lane * 8, &lds[12288 + 8192 + t0 * 512 + 512]); \
            }                                                                  \
        }                                                                      \
        __syncthreads();                                                       \
        _Pragma("unroll")                                                      \
        for (int sb = 0; sb < 2; ++sb) {                                       \
            const int lb = sb * 12288;                                         \
            bf16x8 af[4];                                                      \
            _Pragma("unroll")                                                  \
            for (int i = 0; i < 4; ++i)                                        \
                af[i] = ldfrag(&lds[lb + (4 * wr + i) * 512 + lq * 128 + lm * 8]); \
            _Pragma("unroll")                                                  \
            for (int j = 0; j < 4; ++j) {                                      \
                if (j == (JSKIP)) continue;                                    \
                const bf16x8 bj = ldfrag(&lds[lb + 4096 + (4 * wc + j) * 512 + lq * 128 + lm * 8]); \
                _Pragma("unroll")                                              \
                for (int i = 0; i < 4; ++i) acc[i][j] = MFMA(af[i], bj, acc[i][j]); \
            }                                                                  \
            if (DOLO) {                                                        \
                _Pragma("unroll")                                              \
                for (int j = 0; j < 4; ++j) {                                  \
                    if (j == (JSKIP)) continue;                                \
                    const bf16x8 bl = ldfrag(&lds[lb + 8192 + (4 * wc + j) * 512 + lq * 128 + lm * 8]); \
                    _Pragma("unroll")                                          \
                    for (int i = 0; i < 4; ++i) acc[i][j] = MFMA(af[i], bl, acc[i][j]); \
                }                                                              \
            }                                                                  \
        }                                                                      \
    } while (0)

    // region 0: chunks 0..7   A = S hi, tiled uniform srcs (lo-B if fullsplit)
    for (int s = 0; s < 4; ++s) {
        const ushort* aA = AGG + (size_t)(rt + t0) * 8192 + (size_t)(2 * s) * 512
                         + (size_t)lane * 8;
        GT_STEP(BgAH, BgAL, 2 * s, aA, aA + 8192, aA + 512, aA + 8704, 3, fullsplit);
    }
    // region 1: chunks 8..15  A = S lo (no lo-B: lo*lo dropped)
    for (int s = 4; s < 8; ++s) {
        const ushort* aA = AGG + (size_t)(rt + t0) * 8192 + (size_t)(2 * s) * 512
                         + (size_t)lane * 8;
        GT_STEP(BgAH, BgAL, 2 * s, aA, aA + 8192, aA + 512, aA + 8704, 3, 0);
    }
    // region 2: chunks 16..23 A = hH linear, per-lane srcs (lo-B if fullsplit)
    for (int s = 8; s < 12; ++s) {
        const ushort* aH = HH + (size_t)(rt + t0) * 4096
                         + (size_t)(2 * s - 16) * 32 + hoff;
        GT_STEP(BgBH, BgBL, 2 * s - 16, aH, aH + 4096, aH + 32, aH + 4128, 2, fullsplit);
    }
    // region 3: chunks 24..31 A = hL linear (no lo-B)
    if (useHL) {
        for (int s = 12; s < 16; ++s) {
            const ushort* aL = HL + (size_t)(rt + t0) * 4096
                             + (size_t)(2 * s - 24) * 32 + hoff;
            GT_STEP(BgBH, BgBL, 2 * s - 16, aL, aL + 4096, aL + 32, aL + 4128, 2, 0);
        }
    }
#undef GT_STEP

    // GRU epilogue: col-tile 0..3 = r,z,ni,nh for hidden unit b
    const int b = (2 * cgB + wc) * 16 + lm;
    const float rbias = bsum[b], zbias = bsum[256 + b];
    const float ibias = bni[b], hbias = bnh[b];
#pragma unroll
    for (int i = 0; i < 4; ++i) {
        const int row0 = rb * 128 + wr * 64 + i * 16 + lq * 4;
#pragma unroll
        for (int v = 0; v < 4; ++v) {
            const int row = row0 + v;
            const size_t ho = (size_t)row * 256 + b;  // linear; pads benign
            float hold = bs2f(HH[ho]);
            if (useHL) hold += bs2f(HL[ho]);
            const float r = 1.f / (1.f + expf(-(acc[i][0][v] + rbias)));
            const float z = 1.f / (1.f + expf(-(acc[i][1][v] + zbias)));
            const float nn = tanhf(acc[i][2][v] + ibias + r * (acc[i][3][v] + hbias));
            const float hv = (1.f - z) * nn + z * hold;
            const ushort hi = f2bs(hv);
            HnH[ho] = hi;
            if (useHL) HnL[ho] = f2bs(hv - bs2f(hi));
        }
    }
}

// out[n] = sum_t relu(h[n,t]) * fc_w[t] + fc_b ; one 256-thread block per node
__global__ void final_k(const ushort* __restrict__ HH, const ushort* __restrict__ HL,
                        const void* fcw, const void* fcb,
                        void* out, const int* flags, int useHL, int N) {
    const int n = blockIdx.x;
    const int t = threadIdx.x;
    const int isbf = flags[0];
    const size_t off = (size_t)n * 256 + t;
    float h = bs2f(HH[off]);
    if (useHL) h += bs2f(HL[off]);
    float v = fmaxf(h, 0.f) * ldf(fcw, t, isbf);
#pragma unroll
    for (int offx = 32; offx >= 1; offx >>= 1) v += __shfl_down(v, offx);
    __shared__ float red[4];
    if ((t & 63) == 0) red[t >> 6] = v;
    __syncthreads();
    if (t == 0) {
        const float s = red[0] + red[1] + red[2] + red[3] + ldf(fcb, 0, isbf);
        if (isbf) ((__hip_bfloat16*)out)[n] = __float2bfloat16(s);
        else      ((float*)out)[n] = s;
    }
}

extern "C" void kernel_launch(void* const* d_in, const int* in_sizes, int n_in,
                              void* d_out, int out_size, void* d_ws, size_t ws_size,
                              hipStream_t stream) {
    const int H = HDIM;
    const int N = in_sizes[0] / H;       // 50000
    const int E = in_sizes[2];           // 800000
    const int L = in_sizes[3] / (H * H); // 5
    const int NB = (N + 255) / 256;
    const int nRB = (N + 127) / 128;     // 391
    const size_t NPAD = (size_t)nRB * 128;
    const size_t hHalf = NPAD * 256;     // halves per h plane
    const size_t aggHalf = NPAD * 512;

    char* p = (char*)d_ws;
    int*    flags = (int*)p;              p += 64;
    ushort* AGG  = (ushort*)p;            p += aggHalf * 2;
    ushort* HxH  = (ushort*)p;            p += hHalf * 2;
    ushort* HyH  = (ushort*)p;            p += hHalf * 2;
    float*  wihp = (float*)p;             p += (size_t)L * 768 * 256 * 4;
    ushort* BgAH = (ushort*)p;            p += (size_t)L * 524288 * 2;
    ushort* BgAL = (ushort*)p;            p += (size_t)L * 524288 * 2;
    ushort* BgBH = (ushort*)p;            p += (size_t)524288 * 2;
    ushort* BgBL = (ushort*)p;            p += (size_t)524288 * 2;
    float*  bsum = (float*)p;             p += 512 * 4;
    float*  bni  = (float*)p;             p += 256 * 4;
    float*  bnh  = (float*)p;             p += 256 * 4;
    int*    ptr  = (int*)p;               p += (size_t)(N + 1) * 4;
    int*    cursor = (int*)p;             p += (size_t)N * 4;
    int*    bsumN  = (int*)p;             p += (size_t)NB * 4;
    int*    srcs   = (int*)p;             p += (size_t)E * 4;
    float*  wse    = (float*)p;           p += (size_t)E * 4;
    const size_t need_reduced = (size_t)(p - (char*)d_ws);
    ushort* HxL = (ushort*)p;             // optional hi/lo h planes
    ushort* HyL = (ushort*)(p + hHalf * 2);
    const size_t need_full = need_reduced + 2 * hHalf * 2;
    const int useHL = (ws_size >= need_full) ? 1 : 0;
    if (!useHL) { HxL = HxH; HyL = HyH; }  // never dereferenced when useHL=0

    detect_k<<<dim3(1), dim3(64), 0, stream>>>(d_in[0], d_in[1], flags);
    conv_h0_k<<<dim3((unsigned)NPAD), dim3(256), 0, stream>>>(
        d_in[0], HxH, HxL, flags, useHL, N, NPAD * 256);
    prep1_k<<<dim3((unsigned)(L * 768)), dim3(256), 0, stream>>>(
        d_in[4], d_in[3], wihp, flags);
    prep2_k<<<dim3((unsigned)(L * 2048)), dim3(256), 0, stream>>>(
        wihp, d_in[5], d_in[6], d_in[7],
        BgAH, BgAL, BgBH, BgBL, bsum, bni, bnh, flags, L);

    zero_int_k<<<dim3(NB), dim3(256), 0, stream>>>(cursor, N);
    count_k<<<dim3((E + 255) / 256), dim3(256), 0, stream>>>(d_in[1], cursor, flags, E);
    scan1_k<<<dim3(NB), dim3(256), 0, stream>>>(cursor, ptr, bsumN, N);
    scan2_k<<<dim3(1), dim3(256), 0, stream>>>(bsumN, NB);
    scan3_k<<<dim3(NB), dim3(256), 0, stream>>>(ptr, cursor, bsumN, N, E);
    fill_k<<<dim3((E + 255) / 256), dim3(256), 0, stream>>>(
        d_in[1], d_in[2], cursor, srcs, wse, flags, E);

    const dim3 blk(256);
    const unsigned gGrid = 64u * (unsigned)((nRB + 7) / 8);
    ushort *HcH = HxH, *HcL = HxL, *HnH = HyH, *HnL = HyL;
    for (int l = 0; l < L; ++l) {
        spmm_k<<<dim3((N + 3) / 4), blk, 0, stream>>>(
            HcH, HcL, ptr, srcs, wse, AGG, useHL, N);
        gates_k<<<dim3(gGrid), blk, 0, stream>>>(
            AGG, HcH, HcL,
            BgAH + (size_t)l * 524288, BgAL + (size_t)l * 524288,
            BgBH, BgBL, bsum, bni, bnh, HnH, HnL, flags, useHL, nRB);
        ushort* t;
        t = HcH; HcH = HnH; HnH = t;
        t = HcL; HcL = HnL; HnL = t;
    }
    final_k<<<dim3(N), blk, 0, stream>>>(
        HcH, HcL, d_in[8], d_in[9], d_out, flags, useHL, N);
}